// Round 13
// baseline (53.318 us; speedup 1.0000x reference)
//
#include <hip/hip_runtime.h>

// PatchExtractor: B=64, C=128, H=W=64, M=16, n=15. Bit-exact reformulation:
//   ix = y_cord + j - 7, iy = x_cord + i - 7   (reference swaps x/y coords)
//   valid = (0<=ix<64) && (0<=iy<64)
//   out[p][c][i][j] = valid ? x[b][c][iy][ix] : 0       for c in [0,128)
//   in_bounds (c=128) = valid minus reciprocal-multiply boundary flips:
//     flip iff idx==63 && coord<=62 (per axis)  [XLA lowers /63 -> *fl32(1/63);
//     csn error +2.0..2.2 ulp for coord 56..62 pushes grid past +1.0 at idx 63]
//
// R12 post-mortem: patch-major neutral (47us). R9 (44.9us) spends ~50% of its
// cycles on per-element index VALU (~18 ops: 2 magic-divs + bounds + swizzle
// addr), recomputed 129x per (patch,pos). This version hoists the decode into
// a precomputed per-patch table of pre-swizzled LDS offsets (-1 = masked) +
// ready in_bounds floats, built by a ~2us pre-kernel into __device__ globals
// (1.9MB, L2-resident). Main phase 2 per float4: 1 aligned int4 table load +
// 4x(and,cmp,cndmask,ds_read) + 1 store (~5 VALU/elem). in_bounds channel
// becomes a pure copy. Phase-1 DMA staging (global_load_lds w16, swizzle via
// source permute) unchanged.

constexpr int NP    = 15;
constexpr int NPOS  = NP * NP;          // 225
constexpr int CH    = 128;
constexpr int HH    = 64, WW = 64;
constexpr int PLANE = HH * WW;          // 4096
constexpr int MPB   = 16;               // patches per batch
constexpr int TPAD  = 228;              // padded table stride (57 int4, 912B)
constexpr unsigned PER_PATCH = (CH + 1) * NPOS;   // 29025

__device__ int   g_tbl[1024 * TPAD];    // pre-swizzled LDS word offset or -1
__device__ float g_ibt[1024 * TPAD];    // in_bounds channel values

typedef int   i4  __attribute__((ext_vector_type(4)));
typedef float f4v __attribute__((ext_vector_type(4)));
typedef float f4a __attribute__((ext_vector_type(4), aligned(4)));

__global__ __launch_bounds__(256)
void build_tables(const int* __restrict__ xc, const int* __restrict__ yc) {
  const int p = blockIdx.x, t = threadIdx.x;
  if (t >= TPAD) return;
  int off = -1; float ib = 0.0f;
  if (t < NPOS) {
    const int i  = t / NP;
    const int j  = t - i * NP;
    const int xs = xc[p], ys = yc[p];
    const int ix = ys + j - 7;          // x index from y_cord (reference quirk)
    const int iy = xs + i - 7;
    const bool v = ((unsigned)ix < (unsigned)WW) && ((unsigned)iy < (unsigned)HH);
    if (v) {                            // swizzled addr, matches staging permute
      const int c4 = ix >> 2, w = ix & 3;
      off = (iy << 6) + (((c4 + iy) & 15) << 2) + w;
    }
    const bool xf = (ix == WW - 1) && (ys < WW - 1);
    const bool yf = (iy == HH - 1) && (xs < HH - 1);
    ib = (v && !xf && !yf) ? 1.0f : 0.0f;
  }
  g_tbl[p * TPAD + t] = off;
  g_ibt[p * TPAD + t] = ib;
}

__global__ __launch_bounds__(256)
void patch_tbl(const float* __restrict__ x, float* __restrict__ out) {
  const int cg = blockIdx.x;            // 0..127 = channel, 128 = in_bounds
  const int b  = blockIdx.y;            // batch
  const int t  = threadIdx.x;
  const int wv = t >> 6, lane = t & 63;

  __shared__ float s[PLANE];            // 16 KB plane (linear; swizzle via src)

  if (cg == CH) {
    // in_bounds channel: pure table -> out copy
    for (int m = wv; m < MPB; m += 4) {
      const int p = b * MPB + m;
      const size_t S = (size_t)p * PER_PATCH + (size_t)CH * NPOS;
      if (lane < 56) {
        const f4v o = *reinterpret_cast<const f4v*>(&g_ibt[p * TPAD + 4 * lane]);
        *reinterpret_cast<f4a*>(out + S + 4 * (size_t)lane) = o;
      } else if (lane == 56) {
        out[S + 224] = g_ibt[p * TPAD + 224];
      }
    }
    return;
  }

  // Phase 1: DMA one channel plane HBM->LDS (global_load_lds width=16),
  // source pre-permuted so LDS slot (row,c4') holds global col (c4'-row)&15.
  const float4* __restrict__ src =
      reinterpret_cast<const float4*>(x + ((size_t)b * CH + cg) * PLANE);
#pragma unroll
  for (int k = 0; k < 4; ++k) {
    const int slot  = k * 256 + t;
    const int row   = slot >> 4;
    const int c4p   = slot & 15;
    const int srcf4 = (row << 4) + ((c4p - row) & 15);
    float4* ldsbase = reinterpret_cast<float4*>(s) + k * 256 + (t & 192);
    __builtin_amdgcn_global_load_lds(
        (const __attribute__((address_space(1))) void*)(src + srcf4),
        (__attribute__((address_space(3))) void*)ldsbase,
        16, 0, 0);
  }
  __syncthreads();   // drains vmcnt

  // Phase 2: one wave per (patch, channel) chunk; offsets from table.
  for (int m = wv; m < MPB; m += 4) {
    const int p = b * MPB + m;
    const size_t S = (size_t)p * PER_PATCH + (size_t)cg * NPOS;
    if (lane < 56) {
      const i4 o4 = *reinterpret_cast<const i4*>(&g_tbl[p * TPAD + 4 * lane]);
      f4v o;
      o.x = (o4.x >= 0) ? s[o4.x & (PLANE - 1)] : 0.0f;
      o.y = (o4.y >= 0) ? s[o4.y & (PLANE - 1)] : 0.0f;
      o.z = (o4.z >= 0) ? s[o4.z & (PLANE - 1)] : 0.0f;
      o.w = (o4.w >= 0) ? s[o4.w & (PLANE - 1)] : 0.0f;
      *reinterpret_cast<f4a*>(out + S + 4 * (size_t)lane) = o;
    } else if (lane == 56) {
      const int off = g_tbl[p * TPAD + 224];
      out[S + 224] = (off >= 0) ? s[off & (PLANE - 1)] : 0.0f;
    }
  }
}

extern "C" void kernel_launch(void* const* d_in, const int* in_sizes, int n_in,
                              void* d_out, int out_size, void* d_ws, size_t ws_size,
                              hipStream_t stream) {
  const float* x  = (const float*)d_in[0];
  const int*   xc = (const int*)d_in[1];
  const int*   yc = (const int*)d_in[2];
  float* outp = (float*)d_out;

  build_tables<<<1024, 256, 0, stream>>>(xc, yc);
  dim3 grid(CH + 1, 64);   // (channel | in_bounds, batch)
  patch_tbl<<<grid, 256, 0, stream>>>(x, outp);
}

// Round 14
// 46.507 us; speedup vs baseline: 1.1464x; 1.1464x over previous
//
#include <hip/hip_runtime.h>

// PatchExtractor: B=64, C=128, H=W=64, M=16, n=15. Bit-exact reformulation:
//   ix = y_cord + j - 7, iy = x_cord + i - 7   (reference swaps x/y coords)
//   valid = (0<=ix<64) && (0<=iy<64)
//   out[p][c][i][j] = valid ? x[b][c][iy][ix] : 0       for c in [0,128)
//   in_bounds (c=128) = valid minus reciprocal-multiply boundary flips:
//     flip iff idx==63 && coord<=62 (per axis)  [XLA lowers /63 -> *fl32(1/63);
//     csn error +2.0..2.2 ulp for coord 56..62 pushes grid past +1.0 at idx 63]
//
// Eliminated walls: traffic (minimal), LDS conflicts, write locality (R12),
// L3 pollution/nt (R11), per-elem VALU (R13: VALUBusy 25->10% yet SLOWER).
// Remaining suspect: per-block phase serialization -- R9 blocks do
// DMA -> __syncthreads (vmcnt(0) FULL drain of the staging queue) -> compute
// -> exit, at 66% occupancy. This version: persistent 512-thread blocks
// (2x16KB LDS dbuf = 4 blocks/CU = 32 waves/CU = 100% occ), 8 planes per
// block, counted s_waitcnt vmcnt(2) so the next tile's DMA stays in flight
// across the barrier (T3/T4-lite). in_bounds folded in (wave 0, patch=blk).

constexpr int NP    = 15;
constexpr int NPOS  = NP * NP;          // 225
constexpr int CH    = 128;
constexpr int HH    = 64, WW = 64;
constexpr int PLANE = HH * WW;          // 4096
constexpr int MPB   = 16;               // patches per batch
constexpr int TILES = 8;                // planes per block
constexpr unsigned PER_PATCH = (CH + 1) * NPOS;   // 29025

typedef float f4v __attribute__((ext_vector_type(4)));
typedef float f4a __attribute__((ext_vector_type(4), aligned(4)));

__device__ __forceinline__ float sampf(const float* __restrict__ s,
                                       int xs, int ys, int pos) {
  const int i  = pos / NP;              // magic-mul
  const int j  = pos - i * NP;
  const int ix = ys + j - 7;            // x index from y_cord (reference quirk)
  const int iy = xs + i - 7;
  if (((unsigned)ix < (unsigned)WW) && ((unsigned)iy < (unsigned)HH)) {
    const int c4 = ix >> 2, w = ix & 3;
    return s[(iy << 6) + (((c4 + iy) & 15) << 2) + w];
  }
  return 0.0f;
}

__global__ __launch_bounds__(512)
void patch_pipe(const float* __restrict__ x,
                const int* __restrict__ xcord,
                const int* __restrict__ ycord,
                float* __restrict__ out) {
  const int blk = blockIdx.x;           // 0..1023
  const int b   = blk >> 4;             // batch (fixed per block)
  const int cg0 = (blk & 15) * TILES;   // first of 8 consecutive planes
  const int t   = threadIdx.x;
  const int wv  = t >> 6, lane = t & 63;

  __shared__ int   sx[MPB], sy[MPB];
  __shared__ float buf[2][PLANE];       // 2 x 16 KB double buffer

  if (t < MPB) { sx[t] = xcord[b * MPB + t]; sy[t] = ycord[b * MPB + t]; }
  __syncthreads();                      // coords visible; nothing else pending

  // DMA one plane HBM->LDS (global_load_lds w16); source pre-permuted so LDS
  // slot (row,c4') holds global col (c4'-row)&15 (inverse of read swizzle).
  auto stage = [&](int k) {
    const float4* __restrict__ src =
        reinterpret_cast<const float4*>(x + ((size_t)b * CH + cg0 + k) * PLANE);
    float4* dst = reinterpret_cast<float4*>(buf[k & 1]);
#pragma unroll
    for (int i = 0; i < 2; ++i) {
      const int slot  = i * 512 + t;
      const int row   = slot >> 4;
      const int c4p   = slot & 15;
      const int srcf4 = (row << 4) + ((c4p - row) & 15);
      float4* ldsbase = dst + i * 512 + (t & 448);   // wave-uniform base
      __builtin_amdgcn_global_load_lds(
          (const __attribute__((address_space(1))) void*)(src + srcf4),
          (__attribute__((address_space(3))) void*)ldsbase,
          16, 0, 0);
    }
  };

  stage(0);
  for (int k = 0; k < TILES; ++k) {
    if (k + 1 < TILES) {
      stage(k + 1);                                    // prefetch next plane
      asm volatile("s_waitcnt vmcnt(2)" ::: "memory"); // tile k arrived; 2 in flight
    } else {
      asm volatile("s_waitcnt vmcnt(0)" ::: "memory");
    }
    __builtin_amdgcn_sched_barrier(0);
    __builtin_amdgcn_s_barrier();

    // process tile k: 16 chunks; wave wv does patches 2wv, 2wv+1
    const float* __restrict__ s = buf[k & 1];
    const int cg = cg0 + k;
#pragma unroll
    for (int half = 0; half < 2; ++half) {
      const int m  = 2 * wv + half;
      const int xs = sx[m], ys = sy[m];
      const size_t S = (size_t)(b * MPB + m) * PER_PATCH + (size_t)cg * NPOS;
      const int h  = (4 - (int)(S & 3)) & 3;   // head scalars to 16B-align
      const int nq = (NPOS - h) >> 2;          // aligned float4 count (55/56)
      const int rr = NPOS - h - 4 * nq;        // tail scalars

      if (lane < h) out[S + lane] = sampf(s, xs, ys, lane);
      if (lane < nq) {
        const int p0 = h + 4 * lane;
        f4v o;
        o.x = sampf(s, xs, ys, p0);
        o.y = sampf(s, xs, ys, p0 + 1);
        o.z = sampf(s, xs, ys, p0 + 2);
        o.w = sampf(s, xs, ys, p0 + 3);
        *reinterpret_cast<f4a*>(out + S + h + 4 * (size_t)lane) = o;
      }
      if (lane < rr) {
        const int pt = h + 4 * nq + lane;
        out[S + pt] = sampf(s, xs, ys, pt);
      }
    }
    __builtin_amdgcn_s_barrier();       // readers done before buf reuse
  }

  // in_bounds channel (c=128) for patch == blk, no x data needed
  if (wv == 0) {
    const int p  = blk;
    const int xs = xcord[p], ys = ycord[p];
    const size_t S = (size_t)p * PER_PATCH + (size_t)CH * NPOS;
    for (int pos = lane; pos < NPOS; pos += 64) {
      const int i  = pos / NP;
      const int j  = pos - i * NP;
      const int ix = ys + j - 7;
      const int iy = xs + i - 7;
      const bool v  = ((unsigned)ix < (unsigned)WW) && ((unsigned)iy < (unsigned)HH);
      const bool xf = (ix == WW - 1) && (ys < WW - 1);
      const bool yf = (iy == HH - 1) && (xs < HH - 1);
      out[S + pos] = (v && !xf && !yf) ? 1.0f : 0.0f;
    }
  }
}

extern "C" void kernel_launch(void* const* d_in, const int* in_sizes, int n_in,
                              void* d_out, int out_size, void* d_ws, size_t ws_size,
                              hipStream_t stream) {
  const float* x  = (const float*)d_in[0];
  const int*   xc = (const int*)d_in[1];
  const int*   yc = (const int*)d_in[2];
  float* outp = (float*)d_out;

  patch_pipe<<<1024, 512, 0, stream>>>(x, xc, yc, outp);
}

// Round 15
// 43.859 us; speedup vs baseline: 1.2157x; 1.0604x over previous
//
#include <hip/hip_runtime.h>

// PatchExtractor: B=64, C=128, H=W=64, M=16, n=15. Bit-exact reformulation:
//   ix = y_cord + j - 7, iy = x_cord + i - 7   (reference swaps x/y coords)
//   valid = (0<=ix<64) && (0<=iy<64)
//   out[p][c][i][j] = valid ? x[b][c][iy][ix] : 0       for c in [0,128)
//   in_bounds (c=128) = valid minus reciprocal-multiply boundary flips:
//     flip iff idx==63 && coord<=62 (per axis)  [XLA lowers /63 -> *fl32(1/63);
//     csn error +2.0..2.2 ulp for coord 56..62 pushes grid past +1.0 at idx 63]
//
// Refuted walls: traffic (minimal), LDS conflicts, write chunk locality (R12),
// L3 pollution/nt (R11), per-elem VALU (R13), phase pipelining (R14). R9 =
// 44.9us = 89% of the 253MB/6.29TB/s copy-rate roofline (40.2us). Last
// untested mechanism: grid(129,64) round-robin puts adjacent channels of the
// same patch on DIFFERENT XCDs -> abutting 900B write chunks (and consecutive
// read planes) interleave finely across all 8 XCDs at the DRAM controllers.
// This version: 1D remap so each XCD owns 8 whole batches -- per-XCD
// contiguous 16.8MB read and 14.9MB write streams. Otherwise byte-identical
// to R9 (global_load_lds w16 staging, source-permuted swizzle, wave-per-chunk
// float4 writes).

constexpr int NP    = 15;
constexpr int NPOS  = NP * NP;          // 225
constexpr int CH    = 128;
constexpr int HH    = 64, WW = 64;
constexpr int PLANE = HH * WW;          // 4096
constexpr int MPB   = 16;               // patches (units) per batch
constexpr unsigned PER_PATCH = (CH + 1) * NPOS;   // 29025

typedef float f4v __attribute__((ext_vector_type(4)));
typedef float f4a __attribute__((ext_vector_type(4), aligned(4)));

__device__ __forceinline__ float sample(const float* __restrict__ s,
                                        int xs, int ys, int pos) {
  const int i  = pos / NP;              // magic-mul
  const int j  = pos - i * NP;
  const int ix = ys + j - 7;            // x index from y_cord (reference quirk)
  const int iy = xs + i - 7;
  if (((unsigned)ix < (unsigned)WW) && ((unsigned)iy < (unsigned)HH)) {
    const int c4 = ix >> 2, w = ix & 3;
    return s[(iy << 6) + (((c4 + iy) & 15) << 2) + w];
  }
  return 0.0f;
}

__global__ __launch_bounds__(256)
void patch_xcd(const float* __restrict__ x,
               const int* __restrict__ xcord,
               const int* __restrict__ ycord,
               float* __restrict__ out) {
  // XCD-partition remap: bid%8 = XCD (HW round-robin); each XCD owns 8 batches.
  const int bid = blockIdx.x;           // 0..8255
  const int xcd = bid & 7;
  const int loc = bid >> 3;             // 0..1031 = 129 cg x 8 local batches
  const int b   = (xcd << 3) + (loc & 7);
  const int cg  = loc >> 3;             // 0..127 = channel, 128 = in_bounds
  const int t   = threadIdx.x;

  __shared__ int    sx[MPB], sy[MPB];
  __shared__ float4 s4[HH * (WW / 4)];  // 16 KB plane (linear; swizzle via src)

  if (t < MPB) { sx[t] = xcord[b * MPB + t]; sy[t] = ycord[b * MPB + t]; }

  if (cg == CH) {
    // in_bounds channel: no x data needed (0.8% of work)
    __syncthreads();
    for (int e = t; e < MPB * NPOS; e += 256) {
      const int p   = e / NPOS;
      const int pos = e - p * NPOS;
      const int i  = pos / NP;
      const int j  = pos - i * NP;
      const int xs = sx[p], ys = sy[p];
      const int ix = ys + j - 7;
      const int iy = xs + i - 7;
      const bool v = ((unsigned)ix < (unsigned)WW) && ((unsigned)iy < (unsigned)HH);
      const bool xflip = (ix == WW - 1) && (ys < WW - 1);
      const bool yflip = (iy == HH - 1) && (xs < HH - 1);
      out[(size_t)(b * MPB + p) * PER_PATCH + (size_t)CH * NPOS + pos] =
          (v && !xflip && !yflip) ? 1.0f : 0.0f;
    }
    return;
  }

  // Phase 1: DMA one channel plane HBM->LDS (global_load_lds width=16),
  // source pre-permuted so LDS slot (row,c4') holds global col (c4'-row)&15.
  const float4* __restrict__ src =
      reinterpret_cast<const float4*>(x + ((size_t)b * CH + cg) * PLANE);
#pragma unroll
  for (int k = 0; k < 4; ++k) {
    const int slot  = k * 256 + t;            // LDS float4 slot this lane fills
    const int row   = slot >> 4;
    const int c4p   = slot & 15;
    const int srcf4 = (row << 4) + ((c4p - row) & 15);
    float4* ldsbase = &s4[k * 256 + (t & 192)];   // wave-uniform base
    __builtin_amdgcn_global_load_lds(
        (const __attribute__((address_space(1))) void*)(src + srcf4),
        (__attribute__((address_space(3))) void*)ldsbase,
        16, 0, 0);
  }
  __syncthreads();   // drains vmcnt

  // Phase 2: one wave per (patch, channel) chunk of 225 consecutive floats.
  const float* __restrict__ s = reinterpret_cast<const float*>(s4);
  const int wv   = t >> 6;              // wave 0..3
  const int lane = t & 63;
  for (int p = wv; p < MPB; p += 4) {
    const int xs = sx[p], ys = sy[p];
    const size_t Bp = (size_t)(b * MPB + p) * PER_PATCH + (size_t)cg * NPOS;
    const int h  = (4 - (int)(Bp & 3)) & 3;       // head scalars to align
    const int nq = (NPOS - h) >> 2;               // aligned float4 count (55/56)
    const int r  = NPOS - h - 4 * nq;             // tail scalars

    if (lane < h)
      out[Bp + lane] = sample(s, xs, ys, lane);

    if (lane < nq) {
      const int p0 = h + 4 * lane;
      f4v o;
      o.x = sample(s, xs, ys, p0);
      o.y = sample(s, xs, ys, p0 + 1);
      o.z = sample(s, xs, ys, p0 + 2);
      o.w = sample(s, xs, ys, p0 + 3);
      *reinterpret_cast<f4a*>(out + Bp + h + 4 * (size_t)lane) = o;
    }

    if (lane < r) {
      const int pt = h + 4 * nq + lane;
      out[Bp + pt] = sample(s, xs, ys, pt);
    }
  }
}

extern "C" void kernel_launch(void* const* d_in, const int* in_sizes, int n_in,
                              void* d_out, int out_size, void* d_ws, size_t ws_size,
                              hipStream_t stream) {
  const float* x  = (const float*)d_in[0];
  const int*   xc = (const int*)d_in[1];
  const int*   yc = (const int*)d_in[2];
  float* outp = (float*)d_out;

  patch_xcd<<<(CH + 1) * 64, 256, 0, stream>>>(x, xc, yc, outp);
}